// Round 4
// baseline (121.330 us; speedup 1.0000x reference)
//
#include <hip/hip_runtime.h>
#include <math.h>

// AttnSum3d via bf16-split MFMA + symmetry:
//   X = x*mask;  Y = [bf16_hi(X) | bf16_lo(X)]  (L x 256 bf16, exact to ~2^-17)
//   S = Y Y^T symmetric => softmax(S,axis=1) col stats == row stats, and tile
//   (i,j) == tile(j,i)^T: compute only upper-triangle tiles (136 of 256) and
//   extract BOTH row-direction and col-direction partials from each tile.
//   attn_mean = 1/L exactly;  out[b,0,d] = (1/L) sum_l X[l,d] * r[l],
//   r[l] = sum_m exp(S[l,m]-cmax[m]) / csum[m].
// GEMM structure per tile: m97-style (BK=128 chunks, 16x16x32 MFMA, gload_lds
// w16, 16B-slot XOR swizzle by row&15 baked into Y's global layout; measured
// zero LDS bank conflicts -- addressing kept identical to R2/R3 kernel).

constexpr int NB = 16, NL = 2048, ND = 128;
constexpr int ROWS_US = 256;  // ushorts per Y row (K_eff = 256 bf16)

typedef __attribute__((ext_vector_type(8))) short short8;
typedef __attribute__((ext_vector_type(4))) float f32x4;

__device__ __forceinline__ unsigned short f2bf(float f) {
  unsigned u = __builtin_bit_cast(unsigned, f);
  u += 0x7FFFu + ((u >> 16) & 1u);
  return (unsigned short)(u >> 16);
}
__device__ __forceinline__ float bf2f(unsigned short h) {
  unsigned u = ((unsigned)h) << 16;
  return __builtin_bit_cast(float, u);
}

__device__ __forceinline__ void stage16(const unsigned short* g, unsigned short* l) {
  __builtin_amdgcn_global_load_lds(
      (const __attribute__((address_space(1))) unsigned int*)g,
      (__attribute__((address_space(3))) unsigned int*)l, 16, 0, 0);
}

// Y layout: row r = b*NL+l occupies 512 B. Slot s (16 B = 8 bf16; s<16 hi half,
// s>=16 lo half) stored at position s ^ (r&15) within its half.
__global__ __launch_bounds__(256) void k_prep(const float* __restrict__ x,
                                              const float* __restrict__ mask,
                                              unsigned short* __restrict__ Y) {
  const int gid = blockIdx.x * 256 + threadIdx.x;  // one float4 (4 d-elems)
  const int row = gid >> 5;
  const int dq = gid & 31;
  const float4 v = reinterpret_cast<const float4*>(x)[gid];
  const float m = mask[row];
  const float f0 = v.x * m, f1 = v.y * m, f2 = v.z * m, f3 = v.w * m;
  const unsigned short h0 = f2bf(f0), h1 = f2bf(f1), h2 = f2bf(f2), h3 = f2bf(f3);
  const unsigned short e0 = f2bf(f0 - bf2f(h0)), e1 = f2bf(f1 - bf2f(h1)),
                       e2 = f2bf(f2 - bf2f(h2)), e3 = f2bf(f3 - bf2f(h3));
  unsigned short* Yr = Y + (size_t)row * ROWS_US;
  const int sx = dq >> 1, half8 = (dq & 1) * 4;
  const int posH = sx ^ (row & 15);
  const int posL = 16 + (sx ^ (row & 15));
  *reinterpret_cast<ushort4*>(Yr + posH * 8 + half8) = make_ushort4(h0, h1, h2, h3);
  *reinterpret_cast<ushort4*>(Yr + posL * 8 + half8) = make_ushort4(e0, e1, e2, e3);
}

// Upper-triangle tile decode: t -> (ib <= jb)
__device__ __forceinline__ void tri_decode(int t, int& ib, int& jb) {
  int a = (int)((sqrtf(8.f * (float)t + 1.f) - 1.f) * 0.5f);
  while ((a + 1) * (a + 2) / 2 <= t) ++a;
  while (a * (a + 1) / 2 > t) --a;
  jb = a;
  ib = t - a * (a + 1) / 2;
}

// Shared GEMM body: computes 128x128 tile acc for (row0, col0) of batch b.
#define TILE_GEMM(Yb, row0, col0)                                                     \
  f32x4 acc[4][4];                                                                    \
  _Pragma("unroll") for (int rs = 0; rs < 4; ++rs)                                    \
      _Pragma("unroll") for (int cs = 0; cs < 4; ++cs)                                \
          acc[rs][cs] = f32x4{0.f, 0.f, 0.f, 0.f};                                    \
  for (int c = 0; c < 2; ++c) {                                                       \
    __syncthreads();                                                                  \
    _Pragma("unroll") for (int it = 0; it < 8; ++it) {                                \
      const int idx = tid + 256 * it;                                                 \
      const int r = idx >> 4, s = idx & 15;                                           \
      stage16(Yb + (size_t)(row0 + r) * ROWS_US + c * 128 + s * 8, At + idx * 8);     \
      stage16(Yb + (size_t)(col0 + r) * ROWS_US + c * 128 + s * 8, Bt + idx * 8);     \
    }                                                                                 \
    __syncthreads();                                                                  \
    _Pragma("unroll") for (int t4 = 0; t4 < 4; ++t4) {                                \
      const int sl = 4 * t4 + lhi;                                                    \
      short8 af[4], bf[4];                                                            \
      _Pragma("unroll") for (int q = 0; q < 4; ++q) {                                 \
        const int ra = 64 * wr + 16 * q + llo;                                        \
        af[q] = *(const short8*)(At + ra * 128 + ((sl ^ (ra & 15)) << 3));            \
        const int rb = 64 * wc + 16 * q + llo;                                        \
        bf[q] = *(const short8*)(Bt + rb * 128 + ((sl ^ (rb & 15)) << 3));            \
      }                                                                               \
      _Pragma("unroll") for (int rs = 0; rs < 4; ++rs)                                \
          _Pragma("unroll") for (int cs = 0; cs < 4; ++cs)                            \
              acc[rs][cs] = __builtin_amdgcn_mfma_f32_16x16x32_bf16(af[rs], bf[cs],   \
                                                                    acc[rs][cs], 0, 0, 0); \
    }                                                                                 \
  }

// ---- pass 1: per-tile softmax (max,sum) partials, row AND col direction ----
__global__ __launch_bounds__(256, 2) void k_stats2(const unsigned short* __restrict__ Y,
                                                   float2* __restrict__ pmps) {
  __shared__ alignas(128) char lds[65536];
  unsigned short* At = (unsigned short*)lds;
  unsigned short* Bt = (unsigned short*)(lds + 32768);
  const int b = blockIdx.y;
  int ib, jb;
  tri_decode(blockIdx.x, ib, jb);
  const int row0 = ib * 128, col0 = jb * 128;
  const int tid = threadIdx.x;
  const int lane = tid & 63, wave = tid >> 6;
  const int wr = wave >> 1, wc = wave & 1;
  const int lhi = lane >> 4, llo = lane & 15;
  const unsigned short* Yb = Y + (size_t)b * NL * ROWS_US;

  TILE_GEMM(Yb, row0, col0)

  __syncthreads();
  float* rbuf = (float*)lds;            // [2 wc][128][2]
  float* cbuf = (float*)(lds + 4096);   // [2 wr][128][2]
  // row direction: stats for rows of block ib over cols of block jb
#pragma unroll
  for (int rs = 0; rs < 4; ++rs)
#pragma unroll
    for (int rg = 0; rg < 4; ++rg) {
      const float v0 = acc[rs][0][rg], v1 = acc[rs][1][rg];
      const float v2 = acc[rs][2][rg], v3 = acc[rs][3][rg];
      float m = fmaxf(fmaxf(v0, v1), fmaxf(v2, v3));
#pragma unroll
      for (int mk = 1; mk < 16; mk <<= 1) m = fmaxf(m, __shfl_xor(m, mk));
      float s = __expf(v0 - m) + __expf(v1 - m) + __expf(v2 - m) + __expf(v3 - m);
#pragma unroll
      for (int mk = 1; mk < 16; mk <<= 1) s += __shfl_xor(s, mk);
      if (llo == 0) {
        const int rowl = 64 * wr + 16 * rs + 4 * lhi + rg;
        rbuf[(wc * 128 + rowl) * 2 + 0] = m;
        rbuf[(wc * 128 + rowl) * 2 + 1] = s;
      }
    }
  // col direction (transpose tile): stats for rows of block jb over cols of block ib
  if (ib != jb) {
#pragma unroll
    for (int cs = 0; cs < 4; ++cs) {
      float m = -INFINITY;
#pragma unroll
      for (int rs = 0; rs < 4; ++rs)
#pragma unroll
        for (int rg = 0; rg < 4; ++rg) m = fmaxf(m, acc[rs][cs][rg]);
      m = fmaxf(m, __shfl_xor(m, 16));
      m = fmaxf(m, __shfl_xor(m, 32));
      float s = 0.f;
#pragma unroll
      for (int rs = 0; rs < 4; ++rs)
#pragma unroll
        for (int rg = 0; rg < 4; ++rg) s += __expf(acc[rs][cs][rg] - m);
      s += __shfl_xor(s, 16);
      s += __shfl_xor(s, 32);
      if (lhi == 0) {
        const int coll = 64 * wc + 16 * cs + llo;
        cbuf[(wr * 128 + coll) * 2 + 0] = m;
        cbuf[(wr * 128 + coll) * 2 + 1] = s;
      }
    }
  }
  __syncthreads();
  if (tid < 128) {
    const float m0 = rbuf[tid * 2], s0 = rbuf[tid * 2 + 1];
    const float m1 = rbuf[(128 + tid) * 2], s1 = rbuf[(128 + tid) * 2 + 1];
    const float nm = fmaxf(m0, m1);
    pmps[((size_t)(b * 16 + jb)) * NL + row0 + tid] =
        make_float2(nm, s0 * __expf(m0 - nm) + s1 * __expf(m1 - nm));
    if (ib != jb) {
      const float m2 = cbuf[tid * 2], s2 = cbuf[tid * 2 + 1];
      const float m3 = cbuf[(128 + tid) * 2], s3 = cbuf[(128 + tid) * 2 + 1];
      const float nm2 = fmaxf(m2, m3);
      pmps[((size_t)(b * 16 + ib)) * NL + col0 + tid] =
          make_float2(nm2, s2 * __expf(m2 - nm2) + s3 * __expf(m3 - nm2));
    }
  }
}

// combine 16 (m,s) partials per row -> cmax, 1/csum
__global__ __launch_bounds__(256) void k_comb2(const float2* __restrict__ pmps,
                                               float* __restrict__ cmax,
                                               float* __restrict__ crcp) {
  const int i = blockIdx.x * 256 + threadIdx.x;  // b*NL + row
  const int b = i >> 11, row = i & (NL - 1);
  float m = -INFINITY, s = 0.f;
#pragma unroll
  for (int c = 0; c < 16; ++c) {
    const float2 p = pmps[((size_t)(b * 16 + c)) * NL + row];
    const float nm = fmaxf(m, p.x);
    s = s * __expf(m - nm) + p.y * __expf(p.x - nm);
    m = nm;
  }
  cmax[i] = m;
  crcp[i] = 1.0f / s;
}

// ---- pass 2: per-tile r partials, row AND col direction ----
__global__ __launch_bounds__(256, 2) void k_rowsum2(const unsigned short* __restrict__ Y,
                                                    const float* __restrict__ cmax,
                                                    const float* __restrict__ crcp,
                                                    float* __restrict__ rp) {
  __shared__ alignas(128) char lds[65536];
  unsigned short* At = (unsigned short*)lds;
  unsigned short* Bt = (unsigned short*)(lds + 32768);
  const int b = blockIdx.y;
  int ib, jb;
  tri_decode(blockIdx.x, ib, jb);
  const int row0 = ib * 128, col0 = jb * 128;
  const int tid = threadIdx.x;
  const int lane = tid & 63, wave = tid >> 6;
  const int wr = wave >> 1, wc = wave & 1;
  const int lhi = lane >> 4, llo = lane & 15;
  const unsigned short* Yb = Y + (size_t)b * NL * ROWS_US;

  // preload softmax params (hide latency under GEMM)
  float cmc[4], crc[4];
#pragma unroll
  for (int cs = 0; cs < 4; ++cs) {
    const int colg = b * NL + col0 + 64 * wc + 16 * cs + llo;
    cmc[cs] = cmax[colg];
    crc[cs] = crcp[colg];
  }
  float cmr[16], crr[16];
  if (ib != jb) {
#pragma unroll
    for (int rs = 0; rs < 4; ++rs)
#pragma unroll
      for (int rg = 0; rg < 4; ++rg) {
        const int rowg = b * NL + row0 + 64 * wr + 16 * rs + 4 * lhi + rg;
        cmr[rs * 4 + rg] = cmax[rowg];
        crr[rs * 4 + rg] = crcp[rowg];
      }
  }

  TILE_GEMM(Yb, row0, col0)

  __syncthreads();
  float* rbuf = (float*)lds;           // [2 wc][128]
  float* cbuf = (float*)(lds + 2048);  // [2 wr][128]
#pragma unroll
  for (int rs = 0; rs < 4; ++rs)
#pragma unroll
    for (int rg = 0; rg < 4; ++rg) {
      float t = 0.f;
#pragma unroll
      for (int cs = 0; cs < 4; ++cs)
        t += __expf(acc[rs][cs][rg] - cmc[cs]) * crc[cs];
#pragma unroll
      for (int mk = 1; mk < 16; mk <<= 1) t += __shfl_xor(t, mk);
      if (llo == 0) rbuf[wc * 128 + 64 * wr + 16 * rs + 4 * lhi + rg] = t;
    }
  if (ib != jb) {
#pragma unroll
    for (int cs = 0; cs < 4; ++cs) {
      float u = 0.f;
#pragma unroll
      for (int rs = 0; rs < 4; ++rs)
#pragma unroll
        for (int rg = 0; rg < 4; ++rg)
          u += __expf(acc[rs][cs][rg] - cmr[rs * 4 + rg]) * crr[rs * 4 + rg];
      u += __shfl_xor(u, 16);
      u += __shfl_xor(u, 32);
      if (lhi == 0) cbuf[wr * 128 + 64 * wc + 16 * cs + llo] = u;
    }
  }
  __syncthreads();
  if (tid < 128) {
    rp[((size_t)(b * 16 + jb)) * NL + row0 + tid] = rbuf[tid] + rbuf[128 + tid];
    if (ib != jb)
      rp[((size_t)(b * 16 + ib)) * NL + col0 + tid] = cbuf[tid] + cbuf[128 + tid];
  }
}

// ---- pass 3a: per-(b,seg) partial of sum_l w[l]*x[l,:] ----
__global__ __launch_bounds__(256) void k_outp(const float* __restrict__ x,
                                              const float* __restrict__ mask,
                                              const float* __restrict__ rp,
                                              float* __restrict__ partial) {
  const int b = blockIdx.y;
  const int seg = blockIdx.x;  // 16 segments of 128 rows
  const int tid = threadIdx.x;
  const int l0 = seg * 128;
  __shared__ float w_s[128];
  __shared__ float4 red[8][32];
  if (tid < 128) {
    float s = 0.f;
#pragma unroll
    for (int c = 0; c < 16; ++c) s += rp[((size_t)(b * 16 + c)) * NL + l0 + tid];
    w_s[tid] = s * mask[b * NL + l0 + tid];
  }
  __syncthreads();
  const int dq = tid & 31;
  const int rg = tid >> 5;
  float4 acc = make_float4(0.f, 0.f, 0.f, 0.f);
#pragma unroll 4
  for (int i = 0; i < 16; ++i) {
    const int l = 8 * i + rg;
    const float w = w_s[l];
    const float4 v = *reinterpret_cast<const float4*>(x + ((size_t)b * NL + l0 + l) * ND + 4 * dq);
    acc.x += w * v.x; acc.y += w * v.y; acc.z += w * v.z; acc.w += w * v.w;
  }
  red[rg][dq] = acc;
  __syncthreads();
  if (rg == 0) {
    float4 s = acc;
#pragma unroll
    for (int k = 1; k < 8; ++k) {
      const float4 t = red[k][dq];
      s.x += t.x; s.y += t.y; s.z += t.z; s.w += t.w;
    }
    *reinterpret_cast<float4*>(partial + ((size_t)(b * 16 + seg)) * ND + 4 * dq) = s;
  }
}

// ---- pass 3b: finalize out + constant attn_mean fill ----
__global__ __launch_bounds__(1024) void k_fin(const float* __restrict__ partial,
                                              float* __restrict__ out) {
  const int gid = blockIdx.x * 1024 + threadIdx.x;  // 0..32767
  if (gid < NB * ND) {
    const int b = gid >> 7, d = gid & (ND - 1);
    float s = 0.f;
#pragma unroll
    for (int k = 0; k < 16; ++k) s += partial[(size_t)(b * 16 + k) * ND + d];
    out[gid] = s * (1.0f / NL);
  }
  out[NB * ND + gid] = 1.0f / NL;  // attn_mean == 1/L exactly
}

extern "C" void kernel_launch(void* const* d_in, const int* in_sizes, int n_in,
                              void* d_out, int out_size, void* d_ws, size_t ws_size,
                              hipStream_t stream) {
  const float* x = (const float*)d_in[0];     // [16,2048,128] f32
  const float* mask = (const float*)d_in[1];  // [16,2048] f32
  float* out = (float*)d_out;

  unsigned short* Y = (unsigned short*)d_ws;                  // 16.8 MB
  float2* pmps = (float2*)(Y + (size_t)NB * NL * ROWS_US);    // [NB*16*NL] float2 = 4 MB
  float* rp = (float*)pmps;                                   // aliases pmps (consumed before rp written)
  float* cmax = (float*)(pmps + (size_t)NB * 16 * NL);        // [NB*NL]
  float* crcp = cmax + NB * NL;                               // [NB*NL]
  float* partial = crcp + NB * NL;                            // [NB*16*ND]

  k_prep<<<dim3(NB * NL * ND / 4 / 256), 256, 0, stream>>>(x, mask, Y);
  dim3 g(136, NB);
  k_stats2<<<g, 256, 0, stream>>>(Y, pmps);
  k_comb2<<<dim3(NB * NL / 256), 256, 0, stream>>>(pmps, cmax, crcp);
  k_rowsum2<<<g, 256, 0, stream>>>(Y, cmax, crcp, rp);
  k_outp<<<dim3(16, NB), 256, 0, stream>>>(x, mask, rp, partial);
  k_fin<<<32, 1024, 0, stream>>>(partial, out);
}

// Round 5
// 91.143 us; speedup vs baseline: 1.3312x; 1.3312x over previous
//
#include <hip/hip_runtime.h>
#include <math.h>

// AttnSum3d via bf16-split MFMA + symmetry (balanced strips):
//   X = x*mask;  Y = [bf16_hi(X) | bf16_lo(X)]  (L x 256 bf16, exact to ~2^-17)
//   S = Y Y^T symmetric: compute each unordered 128x128 tile pair once via the
//   wrapped-distance decomposition (row i owns j=(i+d)&15, d=0..7, +d=8 if i<8),
//   extracting BOTH row-direction and col-direction softmax partials per tile.
//   Strips of 4-5 tiles per block (512 blocks total) restore amortization that
//   R4's 1-tile blocks lost. XCD swizzle: each XCD owns 2 batches (Y slice 2.1MB
//   fits its 4MB L2).
//   attn_mean = 1/L exactly;  out[b,0,d] = (1/L) sum_l X[l,d] * r[l],
//   r[l] = sum_m exp(S[l,m]-cmax[m]) / csum[m].
// Partial slots per owner row-block o (10 per batch): 0,1 = own strip halves
// (row-direction, online-accumulated); 2..9 = col-direction from the tile at
// circular distance d=slot-1 (slot 9 exists only for o>=8; combines skip it
// for o<8). Each slot written exactly once per launch.

constexpr int NB = 16, NL = 2048, ND = 128;
constexpr int ROWS_US = 256;  // ushorts per Y row (K_eff = 256 bf16)
constexpr int NSLOT = 10;

typedef __attribute__((ext_vector_type(8))) short short8;
typedef __attribute__((ext_vector_type(4))) float f32x4;

__device__ __forceinline__ unsigned short f2bf(float f) {
  unsigned u = __builtin_bit_cast(unsigned, f);
  u += 0x7FFFu + ((u >> 16) & 1u);
  return (unsigned short)(u >> 16);
}
__device__ __forceinline__ float bf2f(unsigned short h) {
  unsigned u = ((unsigned)h) << 16;
  return __builtin_bit_cast(float, u);
}

__device__ __forceinline__ void stage16(const unsigned short* g, unsigned short* l) {
  __builtin_amdgcn_global_load_lds(
      (const __attribute__((address_space(1))) unsigned int*)g,
      (__attribute__((address_space(3))) unsigned int*)l, 16, 0, 0);
}

// Y layout: row r = b*NL+l occupies 512 B. Slot s (16 B = 8 bf16; s<16 hi half,
// s>=16 lo half) stored at position s ^ (r&15) within its half.
__global__ __launch_bounds__(256) void k_prep(const float* __restrict__ x,
                                              const float* __restrict__ mask,
                                              unsigned short* __restrict__ Y) {
  const int gid = blockIdx.x * 256 + threadIdx.x;  // one float4 (4 d-elems)
  const int row = gid >> 5;
  const int dq = gid & 31;
  const float4 v = reinterpret_cast<const float4*>(x)[gid];
  const float m = mask[row];
  const float f0 = v.x * m, f1 = v.y * m, f2 = v.z * m, f3 = v.w * m;
  const unsigned short h0 = f2bf(f0), h1 = f2bf(f1), h2 = f2bf(f2), h3 = f2bf(f3);
  const unsigned short e0 = f2bf(f0 - bf2f(h0)), e1 = f2bf(f1 - bf2f(h1)),
                       e2 = f2bf(f2 - bf2f(h2)), e3 = f2bf(f3 - bf2f(h3));
  unsigned short* Yr = Y + (size_t)row * ROWS_US;
  const int sx = dq >> 1, half8 = (dq & 1) * 4;
  const int posH = sx ^ (row & 15);
  const int posL = 16 + (sx ^ (row & 15));
  *reinterpret_cast<ushort4*>(Yr + posH * 8 + half8) = make_ushort4(h0, h1, h2, h3);
  *reinterpret_cast<ushort4*>(Yr + posL * 8 + half8) = make_ushort4(e0, e1, e2, e3);
}

// Block decode: each XCD (wgid&7) owns 2 batches entirely (L2 locality).
#define STRIP_DECODE()                                              \
  const int sid = blockIdx.x;                                       \
  const int idx = sid >> 3;                                         \
  const int b = ((sid & 7) << 1) | (idx >> 5);                      \
  const int strip = idx & 31;                                       \
  const int ib = strip >> 1, hf = strip & 1;                        \
  const int d0 = hf * 4;                                            \
  const int nt = (hf == 0) ? 4 : ((ib < 8) ? 5 : 4);                \
  const int row0 = ib * 128;                                        \
  const int tid = threadIdx.x;                                      \
  const int lane = tid & 63, wave = tid >> 6;                       \
  const int wr = wave >> 1, wc = wave & 1;                          \
  const int lhi = lane >> 4, llo = lane & 15;

// 128x128 tile GEMM (BK=128 x2 chunks). Declares acc[4][4] (f32x4) in scope.
#define TILE_GEMM(Yb, row0, col0)                                                     \
  f32x4 acc[4][4];                                                                    \
  _Pragma("unroll") for (int rs = 0; rs < 4; ++rs)                                    \
      _Pragma("unroll") for (int cs = 0; cs < 4; ++cs)                                \
          acc[rs][cs] = f32x4{0.f, 0.f, 0.f, 0.f};                                    \
  for (int c = 0; c < 2; ++c) {                                                       \
    __syncthreads();                                                                  \
    _Pragma("unroll") for (int it = 0; it < 8; ++it) {                                \
      const int idx2 = tid + 256 * it;                                                \
      const int r = idx2 >> 4, s = idx2 & 15;                                         \
      stage16(Yb + (size_t)(row0 + r) * ROWS_US + c * 128 + s * 8, At + idx2 * 8);    \
      stage16(Yb + (size_t)(col0 + r) * ROWS_US + c * 128 + s * 8, Bt + idx2 * 8);    \
    }                                                                                 \
    __syncthreads();                                                                  \
    _Pragma("unroll") for (int t4 = 0; t4 < 4; ++t4) {                                \
      const int sl = 4 * t4 + lhi;                                                    \
      short8 af[4], bf[4];                                                            \
      _Pragma("unroll") for (int q = 0; q < 4; ++q) {                                 \
        const int ra = 64 * wr + 16 * q + llo;                                        \
        af[q] = *(const short8*)(At + ra * 128 + ((sl ^ (ra & 15)) << 3));            \
        const int rb = 64 * wc + 16 * q + llo;                                        \
        bf[q] = *(const short8*)(Bt + rb * 128 + ((sl ^ (rb & 15)) << 3));            \
      }                                                                               \
      _Pragma("unroll") for (int rs = 0; rs < 4; ++rs)                                \
          _Pragma("unroll") for (int cs = 0; cs < 4; ++cs)                            \
              acc[rs][cs] = __builtin_amdgcn_mfma_f32_16x16x32_bf16(af[rs], bf[cs],   \
                                                                    acc[rs][cs], 0, 0, 0); \
    }                                                                                 \
  }

// ---- pass 1: softmax (max,sum) partials ----
__global__ __launch_bounds__(256, 2) void k_stats2(const unsigned short* __restrict__ Y,
                                                   float2* __restrict__ pmps) {
  __shared__ alignas(128) char lds[65536];
  unsigned short* At = (unsigned short*)lds;
  unsigned short* Bt = (unsigned short*)(lds + 32768);
  float* ebuf = (float*)lds;           // [2 wr][128][2] col-dir partials (per tile)
  float* rbuf = (float*)(lds + 8192);  // [2 wc][128][2] row-dir partials (strip end)
  STRIP_DECODE()
  const unsigned short* Yb = Y + (size_t)b * NL * ROWS_US;

  float mx[16], sm[16];
#pragma unroll
  for (int i = 0; i < 16; ++i) { mx[i] = -INFINITY; sm[i] = 0.f; }

  for (int dt = 0; dt < nt; ++dt) {
    const int d = d0 + dt;
    const int jb = (ib + d) & 15;
    const int col0 = jb * 128;
    TILE_GEMM(Yb, row0, col0)
    // row-direction online update (16 regs, no sync)
#pragma unroll
    for (int rs = 0; rs < 4; ++rs)
#pragma unroll
      for (int rg = 0; rg < 4; ++rg) {
        const int i = rs * 4 + rg;
        const float v0 = acc[rs][0][rg], v1 = acc[rs][1][rg];
        const float v2 = acc[rs][2][rg], v3 = acc[rs][3][rg];
        const float tmax = fmaxf(fmaxf(v0, v1), fmaxf(v2, v3));
        const float nm = fmaxf(mx[i], tmax);
        sm[i] = sm[i] * __expf(mx[i] - nm) + __expf(v0 - nm) + __expf(v1 - nm) +
                __expf(v2 - nm) + __expf(v3 - nm);
        mx[i] = nm;
      }
    // col-direction per-tile (owner = jb, slot = 1+d); skip diagonal
    if (d != 0) {
      __syncthreads();  // all waves done with At/Bt reads before ebuf write
#pragma unroll
      for (int cs = 0; cs < 4; ++cs) {
        float m = -INFINITY;
#pragma unroll
        for (int rs = 0; rs < 4; ++rs)
#pragma unroll
          for (int rg = 0; rg < 4; ++rg) m = fmaxf(m, acc[rs][cs][rg]);
        m = fmaxf(m, __shfl_xor(m, 16));
        m = fmaxf(m, __shfl_xor(m, 32));
        float s = 0.f;
#pragma unroll
        for (int rs = 0; rs < 4; ++rs)
#pragma unroll
          for (int rg = 0; rg < 4; ++rg) s += __expf(acc[rs][cs][rg] - m);
        s += __shfl_xor(s, 16);
        s += __shfl_xor(s, 32);
        if (lhi == 0) {
          const int coll = 64 * wc + 16 * cs + llo;
          ebuf[(wr * 128 + coll) * 2 + 0] = m;
          ebuf[(wr * 128 + coll) * 2 + 1] = s;
        }
      }
      __syncthreads();
      if (tid < 128) {
        const float m0 = ebuf[tid * 2], s0 = ebuf[tid * 2 + 1];
        const float m1 = ebuf[(128 + tid) * 2], s1 = ebuf[(128 + tid) * 2 + 1];
        const float nm = fmaxf(m0, m1);
        pmps[((size_t)(b * NSLOT + 1 + d)) * NL + col0 + tid] =
            make_float2(nm, s0 * __expf(m0 - nm) + s1 * __expf(m1 - nm));
      }
    }
  }
  // strip-end row-direction reduce -> slot hf
#pragma unroll
  for (int i = 0; i < 16; ++i) {
    float m = mx[i], s = sm[i];
#pragma unroll
    for (int mk = 1; mk < 16; mk <<= 1) {
      const float m2 = __shfl_xor(m, mk);
      const float s2 = __shfl_xor(s, mk);
      const float nm = fmaxf(m, m2);
      s = s * __expf(m - nm) + s2 * __expf(m2 - nm);
      m = nm;
    }
    mx[i] = m; sm[i] = s;
  }
  __syncthreads();
  if (llo == 0) {
#pragma unroll
    for (int rs = 0; rs < 4; ++rs)
#pragma unroll
      for (int rg = 0; rg < 4; ++rg) {
        const int rowl = 64 * wr + 16 * rs + 4 * lhi + rg;
        rbuf[(wc * 128 + rowl) * 2 + 0] = mx[rs * 4 + rg];
        rbuf[(wc * 128 + rowl) * 2 + 1] = sm[rs * 4 + rg];
      }
  }
  __syncthreads();
  if (tid < 128) {
    const float m0 = rbuf[tid * 2], s0 = rbuf[tid * 2 + 1];
    const float m1 = rbuf[(128 + tid) * 2], s1 = rbuf[(128 + tid) * 2 + 1];
    const float nm = fmaxf(m0, m1);
    pmps[((size_t)(b * NSLOT + hf)) * NL + row0 + tid] =
        make_float2(nm, s0 * __expf(m0 - nm) + s1 * __expf(m1 - nm));
  }
}

// combine partial (m,s) -> cmax, 1/csum
__global__ __launch_bounds__(256) void k_comb2(const float2* __restrict__ pmps,
                                               float* __restrict__ cmax,
                                               float* __restrict__ crcp) {
  const int i = blockIdx.x * 256 + threadIdx.x;  // b*NL + row
  const int b = i >> 11, row = i & (NL - 1);
  const int o = row >> 7;
  float m = -INFINITY, s = 0.f;
#pragma unroll
  for (int c = 0; c < NSLOT; ++c) {
    if (c == 9 && o < 8) continue;  // slot 9 only exists for owners >= 8
    const float2 p = pmps[((size_t)(b * NSLOT + c)) * NL + row];
    const float nm = fmaxf(m, p.x);
    s = s * __expf(m - nm) + p.y * __expf(p.x - nm);
    m = nm;
  }
  cmax[i] = m;
  crcp[i] = 1.0f / s;
}

// ---- pass 2: r partials ----
__global__ __launch_bounds__(256, 2) void k_rowsum2(const unsigned short* __restrict__ Y,
                                                    const float* __restrict__ cmax,
                                                    const float* __restrict__ crcp,
                                                    float* __restrict__ rp) {
  __shared__ alignas(128) char lds[65536];
  unsigned short* At = (unsigned short*)lds;
  unsigned short* Bt = (unsigned short*)(lds + 32768);
  float* ebuf = (float*)lds;           // [2 wr][128]
  float* rbuf = (float*)(lds + 8192);  // [2 wc][128]
  STRIP_DECODE()
  const unsigned short* Yb = Y + (size_t)b * NL * ROWS_US;

  // row-side stats (fixed for the strip), used by col-direction epilogues
  float cmr[16], crr[16];
#pragma unroll
  for (int rs = 0; rs < 4; ++rs)
#pragma unroll
    for (int rg = 0; rg < 4; ++rg) {
      const int rowg = b * NL + row0 + 64 * wr + 16 * rs + 4 * lhi + rg;
      cmr[rs * 4 + rg] = cmax[rowg];
      crr[rs * 4 + rg] = crcp[rowg];
    }

  float racc[16];
#pragma unroll
  for (int i = 0; i < 16; ++i) racc[i] = 0.f;

  for (int dt = 0; dt < nt; ++dt) {
    const int d = d0 + dt;
    const int jb = (ib + d) & 15;
    const int col0 = jb * 128;
    // col-side stats for this tile (issued before GEMM to hide latency)
    float cmc[4], crc[4];
#pragma unroll
    for (int cs = 0; cs < 4; ++cs) {
      const int colg = b * NL + col0 + 64 * wc + 16 * cs + llo;
      cmc[cs] = cmax[colg];
      crc[cs] = crcp[colg];
    }
    TILE_GEMM(Yb, row0, col0)
    // row-direction online accumulate
#pragma unroll
    for (int rs = 0; rs < 4; ++rs)
#pragma unroll
      for (int rg = 0; rg < 4; ++rg) {
        float t = 0.f;
#pragma unroll
        for (int cs = 0; cs < 4; ++cs)
          t += __expf(acc[rs][cs][rg] - cmc[cs]) * crc[cs];
        racc[rs * 4 + rg] += t;
      }
    // col-direction per-tile (owner = jb, slot = 1+d); skip diagonal
    if (d != 0) {
      __syncthreads();
#pragma unroll
      for (int cs = 0; cs < 4; ++cs) {
        float u = 0.f;
#pragma unroll
        for (int rs = 0; rs < 4; ++rs)
#pragma unroll
          for (int rg = 0; rg < 4; ++rg)
            u += __expf(acc[rs][cs][rg] - cmr[rs * 4 + rg]) * crr[rs * 4 + rg];
        u += __shfl_xor(u, 16);
        u += __shfl_xor(u, 32);
        if (lhi == 0) ebuf[wr * 128 + 64 * wc + 16 * cs + llo] = u;
      }
      __syncthreads();
      if (tid < 128)
        rp[((size_t)(b * NSLOT + 1 + d)) * NL + col0 + tid] = ebuf[tid] + ebuf[128 + tid];
    }
  }
  // strip-end row-direction reduce -> slot hf
#pragma unroll
  for (int i = 0; i < 16; ++i) {
    float s = racc[i];
#pragma unroll
    for (int mk = 1; mk < 16; mk <<= 1) s += __shfl_xor(s, mk);
    racc[i] = s;
  }
  __syncthreads();
  if (llo == 0) {
#pragma unroll
    for (int rs = 0; rs < 4; ++rs)
#pragma unroll
      for (int rg = 0; rg < 4; ++rg)
        rbuf[wc * 128 + 64 * wr + 16 * rs + 4 * lhi + rg] = racc[rs * 4 + rg];
  }
  __syncthreads();
  if (tid < 128)
    rp[((size_t)(b * NSLOT + hf)) * NL + row0 + tid] = rbuf[tid] + rbuf[128 + tid];
}

// ---- pass 3a: per-(b,seg) partial of sum_l w[l]*x[l,:] ----
__global__ __launch_bounds__(256) void k_outp(const float* __restrict__ x,
                                              const float* __restrict__ mask,
                                              const float* __restrict__ rp,
                                              float* __restrict__ partial) {
  const int b = blockIdx.y;
  const int seg = blockIdx.x;  // 16 segments of 128 rows; owner block o == seg
  const int tid = threadIdx.x;
  const int l0 = seg * 128;
  __shared__ float w_s[128];
  __shared__ float4 red[8][32];
  if (tid < 128) {
    float s = 0.f;
#pragma unroll
    for (int c = 0; c < NSLOT; ++c) {
      if (c == 9 && seg < 8) continue;
      s += rp[((size_t)(b * NSLOT + c)) * NL + l0 + tid];
    }
    w_s[tid] = s * mask[b * NL + l0 + tid];
  }
  __syncthreads();
  const int dq = tid & 31;
  const int rg = tid >> 5;
  float4 acc = make_float4(0.f, 0.f, 0.f, 0.f);
#pragma unroll 4
  for (int i = 0; i < 16; ++i) {
    const int l = 8 * i + rg;
    const float w = w_s[l];
    const float4 v = *reinterpret_cast<const float4*>(x + ((size_t)b * NL + l0 + l) * ND + 4 * dq);
    acc.x += w * v.x; acc.y += w * v.y; acc.z += w * v.z; acc.w += w * v.w;
  }
  red[rg][dq] = acc;
  __syncthreads();
  if (rg == 0) {
    float4 s = acc;
#pragma unroll
    for (int k = 1; k < 8; ++k) {
      const float4 t = red[k][dq];
      s.x += t.x; s.y += t.y; s.z += t.z; s.w += t.w;
    }
    *reinterpret_cast<float4*>(partial + ((size_t)(b * 16 + seg)) * ND + 4 * dq) = s;
  }
}

// ---- pass 3b: finalize out + constant attn_mean fill ----
__global__ __launch_bounds__(1024) void k_fin(const float* __restrict__ partial,
                                              float* __restrict__ out) {
  const int gid = blockIdx.x * 1024 + threadIdx.x;  // 0..32767
  if (gid < NB * ND) {
    const int b = gid >> 7, d = gid & (ND - 1);
    float s = 0.f;
#pragma unroll
    for (int k = 0; k < 16; ++k) s += partial[(size_t)(b * 16 + k) * ND + d];
    out[gid] = s * (1.0f / NL);
  }
  out[NB * ND + gid] = 1.0f / NL;  // attn_mean == 1/L exactly
}

extern "C" void kernel_launch(void* const* d_in, const int* in_sizes, int n_in,
                              void* d_out, int out_size, void* d_ws, size_t ws_size,
                              hipStream_t stream) {
  const float* x = (const float*)d_in[0];     // [16,2048,128] f32
  const float* mask = (const float*)d_in[1];  // [16,2048] f32
  float* out = (float*)d_out;

  unsigned short* Y = (unsigned short*)d_ws;                  // 16.8 MB
  float2* pmps = (float2*)(Y + (size_t)NB * NL * ROWS_US);    // [NB*NSLOT*NL] float2 = 2.6 MB
  float* rp = (float*)pmps;                                   // aliases pmps (consumed first)
  float* cmax = (float*)(pmps + (size_t)NB * NSLOT * NL);     // [NB*NL]
  float* crcp = cmax + NB * NL;                               // [NB*NL]
  float* partial = crcp + NB * NL;                            // [NB*16*ND]

  k_prep<<<dim3(NB * NL * ND / 4 / 256), 256, 0, stream>>>(x, mask, Y);
  k_stats2<<<dim3(512), 256, 0, stream>>>(Y, pmps);
  k_comb2<<<dim3(NB * NL / 256), 256, 0, stream>>>(pmps, cmax, crcp);
  k_rowsum2<<<dim3(512), 256, 0, stream>>>(Y, cmax, crcp, rp);
  k_outp<<<dim3(16, NB), 256, 0, stream>>>(x, mask, rp, partial);
  k_fin<<<32, 1024, 0, stream>>>(partial, out);
}